// Round 12
// baseline (1490.425 us; speedup 1.0000x reference)
//
#include <hip/hip_runtime.h>

// GADBase diffusion: B=2, H=W=512, 128 iterations of fused diffuse+adjust.
// Register-resident temporal blocking, KS=8 steps/launch with 5-wave WGs:
// 320 threads, 288 active, each owning a VERTICAL PAIR of 4x4 blocks (an 8x4
// strip) of the 96x96 region (24x24 blocks) around a 32x32 output tile.
// The pair shares its middle cv edge-row, so coefficients fit in registers
// (~140 VGPR) where single-block KS=8 (rounds 8-10) spilled.
// 16 diffuse launches + 1 cvch = 17 dispatches (dispatch overhead ~12us each
// dominates total time; round-11 model).
constexpr int Hh = 512, Ww = 512, Bn = 2;
constexpr int SWs = 128;
constexpr float Lf = 0.24f;
constexpr float Kf = 0.03f;
constexpr float EPSf = 1e-8f;
constexpr int NSTEPS = 128;

constexpr int NPIX = Bn * Hh * Ww;        // 524288
constexpr int CVN  = Bn * (Hh - 1) * Ww;  // 523264

constexpr int OT = 32;                    // output tile side
constexpr int KS = 8;                     // steps per launch (128 = 16*8)
constexpr int HALO = 4 * KS;              // 32
constexpr int G = (OT + 2 * HALO) / 4;    // 24x24 block grid per region
constexpr int PRr = G / 2;                // 12 pair rows
constexpr int PCc = G;                    // 24 pair cols
constexpr int NPAIR = PRr * PCc;          // 288 active threads
constexpr int REC = 28;                   // pair record stride (dwords)
constexpr int NTHR = 320;                 // 5 waves
constexpr int NWG = Bn * (Hh / OT) * (Ww / OT);  // 512
constexpr int NLAUNCH = NSTEPS / KS;      // 16

__device__ __forceinline__ int clampi(int v, int lo, int hi) {
  return min(max(v, lo), hi);
}

// ---------------------------------------------------------------------------
// Kernel 1: edge-stopping coefficients cv, ch (once, into d_out slots).
// ---------------------------------------------------------------------------
__global__ __launch_bounds__(256) void cvch_kernel(
    const float* __restrict__ img, const float* __restrict__ guide,
    float* __restrict__ cv, float* __restrict__ ch) {
  int idx = blockIdx.x * blockDim.x + threadIdx.x;
  if (idx >= NPIX) return;
  int x = idx & (Ww - 1);
  int y = (idx >> 9) & (Hh - 1);
  int b = idx >> 18;
  const float inv_k2 = 1.0f / (Kf * Kf);
  const float* f0 = img + (size_t)b * Hh * Ww;
  const float* g0 = guide + (size_t)b * 3 * Hh * Ww;
  const float* g1 = g0 + Hh * Ww;
  const float* g2 = g1 + Hh * Ww;
  int p = y * Ww + x;
  float c0 = f0[p], c1 = g0[p], c2 = g1[p], c3 = g2[p];
  if (y < Hh - 1) {
    int q = p + Ww;
    float m = (fabsf(f0[q] - c0) + fabsf(g0[q] - c1) +
               fabsf(g1[q] - c2) + fabsf(g2[q] - c3)) * 0.25f;
    cv[(b * (Hh - 1) + y) * Ww + x] = 1.0f / (1.0f + m * m * inv_k2);
  }
  if (x < Ww - 1) {
    int q = p + 1;
    float m = (fabsf(f0[q] - c0) + fabsf(g0[q] - c1) +
               fabsf(g1[q] - c2) + fabsf(g2[q] - c3)) * 0.25f;
    ch[(b * Hh + y) * (Ww - 1) + x] = 1.0f / (1.0f + m * m * inv_k2);
  }
}

// ---------------------------------------------------------------------------
// Kernel 2: 8 diffusion+adjust steps per launch, pair-of-blocks per thread.
// Pair record layout (28-dword stride, 24 used): +0 top row f4 (strip row 0),
// +4 bottom row f4 (strip row 7), +8/+12 left col rows 0-3/4-7, +16/+20
// right col rows 0-3/4-7.
// Per step: [sync, read 6xb128], compute strip, [sync, write 6xb128] (R5's
// proven two-barrier flow). Shrinking active set at BLOCK granularity: step s
// computes valid values for blocks [s+1, G-1-s)^2; a pair publishes when it
// intersects that set (garbage sections flow only into invalid blocks; valid
// blocks [s+2, G-2-s)^2 read only valid neighbors). Final central blocks
// [KS, G-KS)^2 = pairs pr in [4,8) x pc in [8,16) = the 32x32 output tile.
// Off-image pixels are decoupled (boundary-crossing coefficients exactly 0).
// ---------------------------------------------------------------------------
__global__ __launch_bounds__(NTHR, 3) void diffuse8_kernel(
    const float* __restrict__ src, float* __restrict__ dst,
    const float* __restrict__ cv, const float* __restrict__ ch,
    const float* __restrict__ source, const float* __restrict__ mask) {
  __shared__ __align__(16) float ebuf[NPAIR * REC];  // 32.2 KB

  int wg = blockIdx.x;
  int b  = wg >> 8;                        // 256 tiles per image
  int t  = wg & 255;
  int Ty0 = (t >> 4) * OT;
  int Tx0 = (t & 15) * OT;

  int tid = threadIdx.x;
  bool act = tid < NPAIR;
  int p  = min(tid, NPAIR - 1);
  int pr = p / PCc, pc = p - pr * PCc;     // pair coords (12 x 24)
  int gy0 = Ty0 - HALO + 8 * pr;           // strip origin (8 rows x 4 cols)
  int gx0 = Tx0 - HALO + 4 * pc;

  // step-invariant LDS record offsets (dwords); rim clamps read own record,
  // those values are never consumed by valid blocks
  int oMy = p * REC;
  int oU  = (pr > 0       ? p - PCc : p) * REC + 4;   // upper pair's bottom row
  int oD  = (pr < PRr - 1 ? p + PCc : p) * REC + 0;   // lower pair's top row
  int oL  = (pc > 0       ? p - 1   : p) * REC + 16;  // left pair's right col
  int oR  = (pc < PCc - 1 ? p + 1   : p) * REC + 8;   // right pair's left col

  const size_t ib = (size_t)b * Hh * Ww;
  const float* S = src + ib;
  float* D = dst + ib;
  const float* cvb = cv + (size_t)b * (Hh - 1) * Ww;
  const float* chb = ch + (size_t)b * Hh * (Ww - 1);

  auto ld4 = [&](int gy, int gx) -> float4 {
    gy = clampi(gy, 0, Hh - 1);
    if (gx < 0)      { float v = S[gy * Ww];          return make_float4(v, v, v, v); }
    if (gx > Ww - 4) { float v = S[gy * Ww + Ww - 1]; return make_float4(v, v, v, v); }
    return *reinterpret_cast<const float4*>(&S[gy * Ww + gx]);
  };

  // --- own 8x4 strip + initial neighbor edges (time 0, from global) ------
  float I[8][4];
#pragma unroll
  for (int rr = 0; rr < 8; ++rr) {
    float4 t4 = ld4(gy0 + rr, gx0);
    I[rr][0] = t4.x; I[rr][1] = t4.y; I[rr][2] = t4.z; I[rr][3] = t4.w;
  }
  float nT[4], nB[4], nL[8], nR[8];
  {
    float4 t4 = ld4(gy0 - 1, gx0);
    nT[0] = t4.x; nT[1] = t4.y; nT[2] = t4.z; nT[3] = t4.w;
    t4 = ld4(gy0 + 8, gx0);
    nB[0] = t4.x; nB[1] = t4.y; nB[2] = t4.z; nB[3] = t4.w;
    int cL = clampi(gx0 - 1, 0, Ww - 1), cR = clampi(gx0 + 4, 0, Ww - 1);
#pragma unroll
    for (int rr = 0; rr < 8; ++rr) {
      int gy = clampi(gy0 + rr, 0, Hh - 1);
      nL[rr] = S[gy * Ww + cL];
      nR[rr] = S[gy * Ww + cR];
    }
  }

  // --- step-invariant coefficients (L folded; image-boundary edges -> 0) -
  float cvk[9][4];                         // edge rows gy0-1 .. gy0+7
#pragma unroll
  for (int k = 0; k < 9; ++k) {
    int ro = gy0 - 1 + k;
    if (ro < 0 || ro > Hh - 2) {
      cvk[k][0] = cvk[k][1] = cvk[k][2] = cvk[k][3] = 0.0f;
    } else if (gx0 < 0) {
      float v = Lf * cvb[ro * Ww];
      cvk[k][0] = cvk[k][1] = cvk[k][2] = cvk[k][3] = v;
    } else if (gx0 > Ww - 4) {
      float v = Lf * cvb[ro * Ww + Ww - 1];
      cvk[k][0] = cvk[k][1] = cvk[k][2] = cvk[k][3] = v;
    } else {
      float4 t4 = *reinterpret_cast<const float4*>(&cvb[ro * Ww + gx0]);
      cvk[k][0] = Lf * t4.x; cvk[k][1] = Lf * t4.y;
      cvk[k][2] = Lf * t4.z; cvk[k][3] = Lf * t4.w;
    }
  }
  float chk[8][5];                         // edge cols gx0-1 .. gx0+3
#pragma unroll
  for (int rr = 0; rr < 8; ++rr) {
    int ri = clampi(gy0 + rr, 0, Hh - 1);
#pragma unroll
    for (int j = 0; j < 5; ++j) {
      int e = gx0 - 1 + j;
      chk[rr][j] = (e >= 0 && e <= Ww - 2) ? Lf * chb[ri * (Ww - 1) + e] : 0.0f;
    }
  }

  // per-block adjust inputs (upper/lower 4x4 blocks have separate cells)
  int sx  = clampi(gx0 >> 2, 0, SWs - 1);
  int sy0 = clampi(gy0 >> 2, 0, SWs - 1);
  int sy1 = clampi((gy0 + 4) >> 2, 0, SWs - 1);
  int si0 = (b * SWs + sy0) * SWs + sx;
  int si1 = (b * SWs + sy1) * SWs + sx;
  float srcv0 = source[si0], srcv1 = source[si1];
  bool  mskv0 = mask[si0] > 0.5f, mskv1 = mask[si1] > 0.5f;

#pragma unroll
  for (int s = 0; s < KS; ++s) {
    if (s > 0) {
      __syncthreads();
      float4 t4;
      t4 = *reinterpret_cast<const float4*>(ebuf + oU);
      nT[0] = t4.x; nT[1] = t4.y; nT[2] = t4.z; nT[3] = t4.w;
      t4 = *reinterpret_cast<const float4*>(ebuf + oD);
      nB[0] = t4.x; nB[1] = t4.y; nB[2] = t4.z; nB[3] = t4.w;
      t4 = *reinterpret_cast<const float4*>(ebuf + oL);
      nL[0] = t4.x; nL[1] = t4.y; nL[2] = t4.z; nL[3] = t4.w;
      t4 = *reinterpret_cast<const float4*>(ebuf + oL + 4);
      nL[4] = t4.x; nL[5] = t4.y; nL[6] = t4.z; nL[7] = t4.w;
      t4 = *reinterpret_cast<const float4*>(ebuf + oR);
      nR[0] = t4.x; nR[1] = t4.y; nR[2] = t4.z; nR[3] = t4.w;
      t4 = *reinterpret_cast<const float4*>(ebuf + oR + 4);
      nR[4] = t4.x; nR[5] = t4.y; nR[6] = t4.z; nR[7] = t4.w;
    }

    // in-place stencil with row/col original-value delay buffers
    float sum0 = 0.0f, sum1 = 0.0f;
    float rowOrig[4];
#pragma unroll
    for (int rr = 0; rr < 8; ++rr) {
      float leftOrig = 0.0f;
#pragma unroll
      for (int c = 0; c < 4; ++c) {
        float cc = I[rr][c];
        float up = (rr == 0) ? nT[c] : rowOrig[c];
        float dn = (rr == 7) ? nB[c] : I[rr + 1][c];
        float lf = (c == 0) ? nL[rr] : leftOrig;
        float rt = (c == 3) ? nR[rr] : I[rr][c + 1];
        float acc = cc + cvk[rr + 1][c] * (dn - cc) - cvk[rr][c] * (cc - up)
                       + chk[rr][c + 1] * (rt - cc) - chk[rr][c] * (cc - lf);
        rowOrig[c] = cc;
        leftOrig = cc;
        I[rr][c] = acc;
        if (rr < 4) sum0 += acc; else sum1 += acc;
      }
    }
    float ratio0 = mskv0 ? 1.0f : __fdividef(srcv0, sum0 * 0.0625f + EPSf);
    float ratio1 = mskv1 ? 1.0f : __fdividef(srcv1, sum1 * 0.0625f + EPSf);
#pragma unroll
    for (int rr = 0; rr < 4; ++rr)
#pragma unroll
      for (int c = 0; c < 4; ++c) I[rr][c] *= ratio0;
#pragma unroll
    for (int rr = 4; rr < 8; ++rr)
#pragma unroll
      for (int c = 0; c < 4; ++c) I[rr][c] *= ratio1;

    if (s == KS - 1) {
      // central pairs == the 32x32 output tile
      if (act && pr >= 4 && pr < 8 && pc >= 8 && pc < 16) {
#pragma unroll
        for (int rr = 0; rr < 8; ++rr)
          *reinterpret_cast<float4*>(&D[(gy0 + rr) * Ww + gx0]) =
              make_float4(I[rr][0], I[rr][1], I[rr][2], I[rr][3]);
      }
    } else {
      __syncthreads();
      // publish if pair intersects the valid block set [s+1, G-1-s)^2
      bool pubR = (2 * pr + 1 >= s + 1) && (2 * pr <= (G - 2) - s);
      bool pubC = (pc >= s + 1) && (pc <= (G - 2) - s);
      if (act && pubR && pubC) {
        float* r = ebuf + oMy;
        *reinterpret_cast<float4*>(r + 0) =
            make_float4(I[0][0], I[0][1], I[0][2], I[0][3]);   // top row
        *reinterpret_cast<float4*>(r + 4) =
            make_float4(I[7][0], I[7][1], I[7][2], I[7][3]);   // bottom row
        *reinterpret_cast<float4*>(r + 8) =
            make_float4(I[0][0], I[1][0], I[2][0], I[3][0]);   // left col 0-3
        *reinterpret_cast<float4*>(r + 12) =
            make_float4(I[4][0], I[5][0], I[6][0], I[7][0]);   // left col 4-7
        *reinterpret_cast<float4*>(r + 16) =
            make_float4(I[0][3], I[1][3], I[2][3], I[3][3]);   // right col 0-3
        *reinterpret_cast<float4*>(r + 20) =
            make_float4(I[4][3], I[5][3], I[6][3], I[7][3]);   // right col 4-7
      }
    }
  }
}

// ---------------------------------------------------------------------------
// Fallback (small ws): one launch per step.
// ---------------------------------------------------------------------------
constexpr int FT = 32;
__global__ __launch_bounds__(64) void step_kernel(
    const float* __restrict__ src, float* __restrict__ dst,
    const float* __restrict__ cv, const float* __restrict__ ch,
    const float* __restrict__ source, const float* __restrict__ mask) {
  __shared__ float sIl[FT + 2][FT + 3];
  int b = blockIdx.z;
  int ty0 = blockIdx.y * FT, tx0 = blockIdx.x * FT;
  const float* I = src + (size_t)b * Hh * Ww;
  int tid = threadIdx.x;
  for (int i = tid; i < (FT + 2) * (FT + 2); i += 64) {
    int ly = i / (FT + 2), lx = i % (FT + 2);
    int gy = max(0, min(Hh - 1, ty0 + ly - 1));
    int gx = max(0, min(Ww - 1, tx0 + lx - 1));
    sIl[ly][lx] = I[gy * Ww + gx];
  }
  __syncthreads();
  int bby = tid >> 3, bbx = tid & 7;
  int py0 = bby * 4, px0 = bbx * 4;
  int gy0 = ty0 + py0, gx0 = tx0 + px0;
  const float* cvb = cv + (size_t)b * (Hh - 1) * Ww;
  const float* chb = ch + (size_t)b * Hh * (Ww - 1);
  float v[4][4]; float sum = 0.0f;
#pragma unroll
  for (int dy = 0; dy < 4; ++dy) {
    int y = gy0 + dy, ly = py0 + dy + 1;
#pragma unroll
    for (int dx = 0; dx < 4; ++dx) {
      int x = gx0 + dx, lx = px0 + dx + 1;
      float cc = sIl[ly][lx];
      float acc = cc;
      if (y < Hh - 1) acc += Lf * cvb[y * Ww + x] * (sIl[ly + 1][lx] - cc);
      if (y > 0)      acc -= Lf * cvb[(y - 1) * Ww + x] * (cc - sIl[ly - 1][lx]);
      if (x < Ww - 1) acc += Lf * chb[y * (Ww - 1) + x] * (sIl[ly][lx + 1] - cc);
      if (x > 0)      acc -= Lf * chb[y * (Ww - 1) + x - 1] * (cc - sIl[ly][lx - 1]);
      v[dy][dx] = acc; sum += acc;
    }
  }
  int sidx = (b * SWs + (gy0 >> 2)) * SWs + (gx0 >> 2);
  float ratio = (mask[sidx] > 0.5f) ? 1.0f : source[sidx] / (sum * 0.0625f + EPSf);
  float* D = dst + (size_t)b * Hh * Ww;
#pragma unroll
  for (int dy = 0; dy < 4; ++dy)
    *reinterpret_cast<float4*>(&D[(gy0 + dy) * Ww + gx0]) =
        make_float4(v[dy][0] * ratio, v[dy][1] * ratio,
                    v[dy][2] * ratio, v[dy][3] * ratio);
}

// ---------------------------------------------------------------------------
extern "C" void kernel_launch(void* const* d_in, const int* in_sizes, int n_in,
                              void* d_out, int out_size, void* d_ws, size_t ws_size,
                              hipStream_t stream) {
  const float* guide  = (const float*)d_in[0];
  const float* ybic   = (const float*)d_in[1];
  const float* source = (const float*)d_in[2];
  const float* mask   = (const float*)d_in[3];

  float* out   = (float*)d_out;
  float* ypred = out;                 // 524288
  float* cv    = out + NPIX;          // 523264
  float* ch    = out + NPIX + CVN;    // 523264

  cvch_kernel<<<dim3((NPIX + 255) / 256), dim3(256), 0, stream>>>(ybic, guide, cv, ch);

  if (ws_size >= (size_t)2 * NPIX * sizeof(float)) {
    float* wsb0 = (float*)d_ws;
    float* wsb1 = wsb0 + NPIX;
    const float* sp = ybic;
    for (int l = 0; l < NLAUNCH; ++l) {
      float* dp = (l == NLAUNCH - 1) ? ypred : ((l & 1) ? wsb1 : wsb0);
      diffuse8_kernel<<<dim3(NWG), dim3(NTHR), 0, stream>>>(sp, dp, cv, ch,
                                                            source, mask);
      sp = dp;
    }
  } else {
    float* wsbuf = (float*)d_ws;
    dim3 grid(Ww / FT, Hh / FT, Bn);
    const float* sp = ybic;
    for (int it = 0; it < NSTEPS; ++it) {
      float* dp = (it & 1) ? ypred : wsbuf;
      step_kernel<<<grid, dim3(64), 0, stream>>>(sp, dp, cv, ch, source, mask);
      sp = dp;
    }
  }
}

// Round 13
// 306.282 us; speedup vs baseline: 4.8662x; 4.8662x over previous
//
#include <hip/hip_runtime.h>

// GADBase diffusion: B=2, H=W=512, 128 iterations of fused diffuse+adjust.
// R11 structure (KS=5, 256 thr, register-resident blocks, parity LDS edge
// buffers, 1 barrier/step) + NEW: per-(tile,thread) coefficient records
// precomputed ONCE into d_ws, so each diffuse launch streams 10 float4s
// instead of ~50 scattered 2KB-stride loads (prologue was ~7us of 12us exec).
constexpr int Hh = 512, Ww = 512, Bn = 2;
constexpr int SWs = 128;
constexpr float Lf = 0.24f;
constexpr float Kf = 0.03f;
constexpr float EPSf = 1e-8f;
constexpr int NSTEPS = 128;

constexpr int NPIX = Bn * Hh * Ww;        // 524288
constexpr int CVN  = Bn * (Hh - 1) * Ww;  // 523264

constexpr int OT = 32;                    // output tile side
constexpr int KS = 5;                     // steps per launch
constexpr int HALO = 4 * KS;              // 20
constexpr int G = (OT + 2 * HALO) / 4;    // 18x18 block grid per region
constexpr int NREC = G * G;               // 324
constexpr int REC = 20;                   // edge record stride (dwords)
constexpr int BUFSZ = NREC * REC;         // 6480 dwords per parity buffer
constexpr int NWG = Bn * (Hh / OT) * (Ww / OT);  // 512
constexpr int CREC = 40;                  // coef record: 40 dwords / thread

__device__ __forceinline__ int clampi(int v, int lo, int hi) {
  return min(max(v, lo), hi);
}
__device__ __forceinline__ int recof(int t) { return t * REC; }

// ---------------------------------------------------------------------------
// Kernel 1: edge-stopping coefficients cv, ch (once, into d_out slots).
// ---------------------------------------------------------------------------
__global__ __launch_bounds__(256) void cvch_kernel(
    const float* __restrict__ img, const float* __restrict__ guide,
    float* __restrict__ cv, float* __restrict__ ch) {
  int idx = blockIdx.x * blockDim.x + threadIdx.x;
  if (idx >= NPIX) return;
  int x = idx & (Ww - 1);
  int y = (idx >> 9) & (Hh - 1);
  int b = idx >> 18;
  const float inv_k2 = 1.0f / (Kf * Kf);
  const float* f0 = img + (size_t)b * Hh * Ww;
  const float* g0 = guide + (size_t)b * 3 * Hh * Ww;
  const float* g1 = g0 + Hh * Ww;
  const float* g2 = g1 + Hh * Ww;
  int p = y * Ww + x;
  float c0 = f0[p], c1 = g0[p], c2 = g1[p], c3 = g2[p];
  if (y < Hh - 1) {
    int q = p + Ww;
    float m = (fabsf(f0[q] - c0) + fabsf(g0[q] - c1) +
               fabsf(g1[q] - c2) + fabsf(g2[q] - c3)) * 0.25f;
    cv[(b * (Hh - 1) + y) * Ww + x] = 1.0f / (1.0f + m * m * inv_k2);
  }
  if (x < Ww - 1) {
    int q = p + 1;
    float m = (fabsf(f0[q] - c0) + fabsf(g0[q] - c1) +
               fabsf(g1[q] - c2) + fabsf(g2[q] - c3)) * 0.25f;
    ch[(b * Hh + y) * (Ww - 1) + x] = 1.0f / (1.0f + m * m * inv_k2);
  }
}

// ---------------------------------------------------------------------------
// Kernel 1b: pack per-(tile,thread) L-folded coefficients into d_ws records.
// Record (CREC=40 dwords): cvk[5][4] at +0..19, chk[4][5] at +20..39.
// Thread mapping EXACTLY matches diffuse5_kernel.
// ---------------------------------------------------------------------------
__global__ __launch_bounds__(256) void coefpack_kernel(
    const float* __restrict__ cv, const float* __restrict__ ch,
    float* __restrict__ crec) {
  int wg = blockIdx.x;
  int b  = wg >> 8;
  int t  = wg & 255;
  int Ty0 = (t >> 4) * OT;
  int Tx0 = (t & 15) * OT;
  int tid = threadIdx.x;
  int by = 1 + (tid >> 4), bx = 1 + (tid & 15);
  int gy0 = Ty0 - HALO + 4 * by;
  int gx0 = Tx0 - HALO + 4 * bx;

  const float* cvb = cv + (size_t)b * (Hh - 1) * Ww;
  const float* chb = ch + (size_t)b * Hh * (Ww - 1);
  float* r = crec + ((size_t)wg * 256 + tid) * CREC;

#pragma unroll
  for (int k = 0; k < 5; ++k) {
    int ro = gy0 - 1 + k;
    float4 o;
    if (ro < 0 || ro > Hh - 2) {
      o = make_float4(0.f, 0.f, 0.f, 0.f);
    } else if (gx0 < 0) {
      float v = Lf * cvb[ro * Ww];
      o = make_float4(v, v, v, v);
    } else if (gx0 > Ww - 4) {
      float v = Lf * cvb[ro * Ww + Ww - 1];
      o = make_float4(v, v, v, v);
    } else {
      float4 t4 = *reinterpret_cast<const float4*>(&cvb[ro * Ww + gx0]);
      o = make_float4(Lf * t4.x, Lf * t4.y, Lf * t4.z, Lf * t4.w);
    }
    *reinterpret_cast<float4*>(r + 4 * k) = o;
  }
#pragma unroll
  for (int rr = 0; rr < 4; ++rr) {
    int ri = clampi(gy0 + rr, 0, Hh - 1);
#pragma unroll
    for (int j = 0; j < 5; ++j) {
      int e = gx0 - 1 + j;
      r[20 + rr * 5 + j] =
          (e >= 0 && e <= Ww - 2) ? Lf * chb[ri * (Ww - 1) + e] : 0.0f;
    }
  }
}

// ---------------------------------------------------------------------------
// Kernel 2: up to 5 diffusion+adjust steps per launch, block state in regs.
// 256 threads = interior 16x16 blocks of an 18x18 block grid (72x72 region
// around a 32x32 output tile). Coefficients: 10 streaming float4 loads from
// the precomputed record. Parity-double-buffered LDS edge records -> one
// barrier per step. Shrinking active set as in R5/R11 (proven).
// ---------------------------------------------------------------------------
__global__ __launch_bounds__(256, 3) void diffuse5_kernel(
    const float* __restrict__ src, float* __restrict__ dst,
    const float* __restrict__ crec,
    const float* __restrict__ source, const float* __restrict__ mask,
    int nsteps) {
  __shared__ __align__(16) float ebuf[2 * BUFSZ];  // 51.8 KB (2 parity bufs)

  int wg = blockIdx.x;
  int b  = wg >> 8;                        // 256 tiles per image
  int t  = wg & 255;
  int Ty0 = (t >> 4) * OT;
  int Tx0 = (t & 15) * OT;

  int tid = threadIdx.x;
  int by = 1 + (tid >> 4), bx = 1 + (tid & 15);
  int gy0 = Ty0 - HALO + 4 * by;           // block origin (may be off-image)
  int gx0 = Tx0 - HALO + 4 * bx;

  // step-invariant record offsets (dwords) within a parity buffer
  int blk = by * G + bx;
  int oMy = recof(blk);
  int oU  = recof(blk - G) + 4;            // upper neighbor's bottom row
  int oD  = recof(blk + G) + 0;            // lower neighbor's top row
  int oL  = recof(blk - 1) + 12;           // left neighbor's right col
  int oR  = recof(blk + 1) + 8;            // right neighbor's left col

  const size_t ib = (size_t)b * Hh * Ww;
  const float* S = src + ib;
  float* D = dst + ib;

  auto ld4 = [&](int gy, int gx) -> float4 {
    gy = clampi(gy, 0, Hh - 1);
    if (gx < 0)      { float v = S[gy * Ww];          return make_float4(v, v, v, v); }
    if (gx > Ww - 4) { float v = S[gy * Ww + Ww - 1]; return make_float4(v, v, v, v); }
    return *reinterpret_cast<const float4*>(&S[gy * Ww + gx]);
  };

  // --- streaming coefficient load (precomputed, L folded, borders zeroed) -
  float cvk[5][4];
  float chk[4][5];
  {
    const float* r = crec + ((size_t)wg * 256 + tid) * CREC;
#pragma unroll
    for (int k = 0; k < 5; ++k) {
      float4 t4 = *reinterpret_cast<const float4*>(r + 4 * k);
      cvk[k][0] = t4.x; cvk[k][1] = t4.y; cvk[k][2] = t4.z; cvk[k][3] = t4.w;
    }
#pragma unroll
    for (int q = 0; q < 5; ++q) {
      float4 t4 = *reinterpret_cast<const float4*>(r + 20 + 4 * q);
      chk[0][0 + 0] = (q == 0) ? t4.x : chk[0][0];  // placeholder, replaced below
    }
    // unpack chk linearly (20 floats at +20)
#pragma unroll
    for (int rr = 0; rr < 4; ++rr)
#pragma unroll
      for (int j = 0; j < 5; ++j) chk[rr][j] = r[20 + rr * 5 + j];
  }

  // --- own 4x4 block + initial neighbor edges (time 0, from global) ------
  float I[4][4];
#pragma unroll
  for (int r = 0; r < 4; ++r) {
    float4 t4 = ld4(gy0 + r, gx0);
    I[r][0] = t4.x; I[r][1] = t4.y; I[r][2] = t4.z; I[r][3] = t4.w;
  }
  float nT[4], nB[4], nL[4], nR[4];
  {
    float4 t4 = ld4(gy0 - 1, gx0);
    nT[0] = t4.x; nT[1] = t4.y; nT[2] = t4.z; nT[3] = t4.w;
    t4 = ld4(gy0 + 4, gx0);
    nB[0] = t4.x; nB[1] = t4.y; nB[2] = t4.z; nB[3] = t4.w;
    int cL = clampi(gx0 - 1, 0, Ww - 1), cR = clampi(gx0 + 4, 0, Ww - 1);
#pragma unroll
    for (int r = 0; r < 4; ++r) {
      int gy = clampi(gy0 + r, 0, Hh - 1);
      nL[r] = S[gy * Ww + cL];
      nR[r] = S[gy * Ww + cR];
    }
  }

  int sy = clampi(gy0 >> 2, 0, SWs - 1);
  int sx = clampi(gx0 >> 2, 0, SWs - 1);
  int sidx = (b * SWs + sy) * SWs + sx;
  float srcv = source[sidx];
  bool mskv = mask[sidx] > 0.5f;

#pragma unroll
  for (int s = 0; s < KS; ++s) {
    if (s >= nsteps) break;                // uniform; outside barrier region
    if (s > 0) {
      // read neighbor edges published at step s-1 (parity (s-1)&1)
      const float* eb = ebuf + ((s - 1) & 1) * BUFSZ;
      float4 t4;
      t4 = *reinterpret_cast<const float4*>(eb + oU);
      nT[0] = t4.x; nT[1] = t4.y; nT[2] = t4.z; nT[3] = t4.w;
      t4 = *reinterpret_cast<const float4*>(eb + oD);
      nB[0] = t4.x; nB[1] = t4.y; nB[2] = t4.z; nB[3] = t4.w;
      t4 = *reinterpret_cast<const float4*>(eb + oL);
      nL[0] = t4.x; nL[1] = t4.y; nL[2] = t4.z; nL[3] = t4.w;
      t4 = *reinterpret_cast<const float4*>(eb + oR);
      nR[0] = t4.x; nR[1] = t4.y; nR[2] = t4.z; nR[3] = t4.w;
    }

    float V[4][4];
    float sum = 0.0f;
#pragma unroll
    for (int r = 0; r < 4; ++r)
#pragma unroll
      for (int c = 0; c < 4; ++c) {
        float cc = I[r][c];
        float up = (r == 0) ? nT[c] : I[r - 1][c];
        float dn = (r == 3) ? nB[c] : I[r + 1][c];
        float lf = (c == 0) ? nL[r] : I[r][c - 1];
        float rt = (c == 3) ? nR[r] : I[r][c + 1];
        float acc = cc + cvk[r + 1][c] * (dn - cc) - cvk[r][c] * (cc - up)
                       + chk[r][c + 1] * (rt - cc) - chk[r][c] * (cc - lf);
        V[r][c] = acc;
        sum += acc;
      }
    float ratio = mskv ? 1.0f : __fdividef(srcv, sum * 0.0625f + EPSf);
#pragma unroll
    for (int r = 0; r < 4; ++r)
#pragma unroll
      for (int c = 0; c < 4; ++c) I[r][c] = V[r][c] * ratio;

    if (s == nsteps - 1) {
      // final values -> global (central 8x8 blocks == the 32x32 output tile)
      if (by >= 5 && by < 13 && bx >= 5 && bx < 13) {
#pragma unroll
        for (int r = 0; r < 4; ++r)
          *reinterpret_cast<float4*>(&D[(gy0 + r) * Ww + gx0]) =
              make_float4(I[r][0], I[r][1], I[r][2], I[r][3]);
      }
    } else {
      // publish edges to parity buffer s&1, then ONE barrier
      float* eb = ebuf + (s & 1) * BUFSZ;
      if (by > s && by < G - 1 - s && bx > s && bx < G - 1 - s) {
        *reinterpret_cast<float4*>(eb + oMy + 0) =
            make_float4(I[0][0], I[0][1], I[0][2], I[0][3]);   // top row
        *reinterpret_cast<float4*>(eb + oMy + 4) =
            make_float4(I[3][0], I[3][1], I[3][2], I[3][3]);   // bottom row
        *reinterpret_cast<float4*>(eb + oMy + 8) =
            make_float4(I[0][0], I[1][0], I[2][0], I[3][0]);   // left col
        *reinterpret_cast<float4*>(eb + oMy + 12) =
            make_float4(I[0][3], I[1][3], I[2][3], I[3][3]);   // right col
      }
      __syncthreads();
    }
  }
}

// ---------------------------------------------------------------------------
// Fallback (small ws): one launch per step.
// ---------------------------------------------------------------------------
constexpr int FT = 32;
__global__ __launch_bounds__(64) void step_kernel(
    const float* __restrict__ src, float* __restrict__ dst,
    const float* __restrict__ cv, const float* __restrict__ ch,
    const float* __restrict__ source, const float* __restrict__ mask) {
  __shared__ float sIl[FT + 2][FT + 3];
  int b = blockIdx.z;
  int ty0 = blockIdx.y * FT, tx0 = blockIdx.x * FT;
  const float* I = src + (size_t)b * Hh * Ww;
  int tid = threadIdx.x;
  for (int i = tid; i < (FT + 2) * (FT + 2); i += 64) {
    int ly = i / (FT + 2), lx = i % (FT + 2);
    int gy = max(0, min(Hh - 1, ty0 + ly - 1));
    int gx = max(0, min(Ww - 1, tx0 + lx - 1));
    sIl[ly][lx] = I[gy * Ww + gx];
  }
  __syncthreads();
  int bby = tid >> 3, bbx = tid & 7;
  int py0 = bby * 4, px0 = bbx * 4;
  int gy0 = ty0 + py0, gx0 = tx0 + px0;
  const float* cvb = cv + (size_t)b * (Hh - 1) * Ww;
  const float* chb = ch + (size_t)b * Hh * (Ww - 1);
  float v[4][4]; float sum = 0.0f;
#pragma unroll
  for (int dy = 0; dy < 4; ++dy) {
    int y = gy0 + dy, ly = py0 + dy + 1;
#pragma unroll
    for (int dx = 0; dx < 4; ++dx) {
      int x = gx0 + dx, lx = px0 + dx + 1;
      float cc = sIl[ly][lx];
      float acc = cc;
      if (y < Hh - 1) acc += Lf * cvb[y * Ww + x] * (sIl[ly + 1][lx] - cc);
      if (y > 0)      acc -= Lf * cvb[(y - 1) * Ww + x] * (cc - sIl[ly - 1][lx]);
      if (x < Ww - 1) acc += Lf * chb[y * (Ww - 1) + x] * (sIl[ly][lx + 1] - cc);
      if (x > 0)      acc -= Lf * chb[y * (Ww - 1) + x - 1] * (cc - sIl[ly][lx - 1]);
      v[dy][dx] = acc; sum += acc;
    }
  }
  int sidx = (b * SWs + (gy0 >> 2)) * SWs + (gx0 >> 2);
  float ratio = (mask[sidx] > 0.5f) ? 1.0f : source[sidx] / (sum * 0.0625f + EPSf);
  float* D = dst + (size_t)b * Hh * Ww;
#pragma unroll
  for (int dy = 0; dy < 4; ++dy)
    *reinterpret_cast<float4*>(&D[(gy0 + dy) * Ww + gx0]) =
        make_float4(v[dy][0] * ratio, v[dy][1] * ratio,
                    v[dy][2] * ratio, v[dy][3] * ratio);
}

// ---------------------------------------------------------------------------
extern "C" void kernel_launch(void* const* d_in, const int* in_sizes, int n_in,
                              void* d_out, int out_size, void* d_ws, size_t ws_size,
                              hipStream_t stream) {
  const float* guide  = (const float*)d_in[0];
  const float* ybic   = (const float*)d_in[1];
  const float* source = (const float*)d_in[2];
  const float* mask   = (const float*)d_in[3];

  float* out   = (float*)d_out;
  float* ypred = out;                 // 524288
  float* cv    = out + NPIX;          // 523264
  float* ch    = out + NPIX + CVN;    // 523264

  cvch_kernel<<<dim3((NPIX + 255) / 256), dim3(256), 0, stream>>>(ybic, guide, cv, ch);

  size_t needPing = (size_t)2 * NPIX * sizeof(float);                // 4 MB
  size_t needCoef = (size_t)NWG * 256 * CREC * sizeof(float);        // 21 MB

  if (ws_size >= needPing + needCoef) {
    float* wsb0 = (float*)d_ws;
    float* wsb1 = wsb0 + NPIX;
    float* crec = wsb1 + NPIX;
    coefpack_kernel<<<dim3(NWG), dim3(256), 0, stream>>>(cv, ch, crec);
    const float* sp = ybic;
    int done = 0, l = 0;
    while (done < NSTEPS) {
      int ns = (NSTEPS - done >= KS) ? KS : (NSTEPS - done);   // 25x5 + 1x3
      bool lastL = (done + ns == NSTEPS);
      float* dp = lastL ? ypred : ((l & 1) ? wsb1 : wsb0);
      diffuse5_kernel<<<dim3(NWG), dim3(256), 0, stream>>>(sp, dp, crec,
                                                           source, mask, ns);
      sp = dp; done += ns; ++l;
    }
  } else {
    float* wsbuf = (float*)d_ws;
    dim3 grid(Ww / FT, Hh / FT, Bn);
    const float* sp = ybic;
    for (int it = 0; it < NSTEPS; ++it) {
      float* dp = (it & 1) ? ypred : wsbuf;
      step_kernel<<<grid, dim3(64), 0, stream>>>(sp, dp, cv, ch, source, mask);
      sp = dp;
    }
  }
}